// Round 18
// baseline (126.655 us; speedup 1.0000x reference)
//
#include <hip/hip_runtime.h>
#include <math.h>

#define TIME_N 65536
#define HALFN  1024
#define NBINS  1025
#define NFRAMES 64
#define FCHUNK 16
#define NCHUNK (NFRAMES / FCHUNK)   // 4

typedef float vf2 __attribute__((ext_vector_type(2)));

// ---------------------------------------------------------------------------
// Kernel 1: channel mixing  out[b,d,t] = sum_c x[b,c,t] * M[c,d]
// v2: M streamed from global (L1-resident 16 KB, half-wave-uniform -> one
// transaction per 4 d), thread owns 8d x 4t (stride-32 t): per c-iter
// 4 conflict-free scalar LDS reads + 2 global float4 M + 32 FMA.
// LDS 33.8 KB -> 4 blocks/CU.
// ---------------------------------------------------------------------------
#define TT 128
__global__ __launch_bounds__(256) void mix_kernel(const float* __restrict__ x,
                                                  const float* __restrict__ M,
                                                  float* __restrict__ out) {
    __shared__ float xt[64][132];   // pad 4: float4-aligned rows, bank map 4c+tq
    const int b   = blockIdx.y;
    const int t0  = blockIdx.x * TT;
    const int tid = threadIdx.x;

    // fill: 64 rows x 128 floats = 2048 float4 / 256 threads = 8 each
    for (int r = 0; r < 8; ++r) {
        int fi = tid + r * 256;          // 0..2047
        int c  = fi >> 5;
        int t4 = fi & 31;
        float4 v = *reinterpret_cast<const float4*>(
            x + (size_t)(b * 64 + c) * TIME_N + t0 + t4 * 4);
        *reinterpret_cast<float4*>(&xt[c][t4 * 4]) = v;
    }
    __syncthreads();

    const int dq = tid >> 5;   // 0..7  -> d = 8dq..8dq+7
    const int tq = tid & 31;   // t = t0 + tq + 32j, j<4

    float acc[8][4];
#pragma unroll
    for (int i = 0; i < 8; ++i)
#pragma unroll
        for (int j = 0; j < 4; ++j) acc[i][j] = 0.f;

#pragma unroll 2
    for (int c = 0; c < 64; ++c) {
        float4 m0 = *reinterpret_cast<const float4*>(M + c * 64 + 8 * dq);
        float4 m1 = *reinterpret_cast<const float4*>(M + c * 64 + 8 * dq + 4);
        float xv[4];
#pragma unroll
        for (int j = 0; j < 4; ++j) xv[j] = xt[c][tq + 32 * j];
#pragma unroll
        for (int j = 0; j < 4; ++j) {
            acc[0][j] += xv[j] * m0.x;
            acc[1][j] += xv[j] * m0.y;
            acc[2][j] += xv[j] * m0.z;
            acc[3][j] += xv[j] * m0.w;
            acc[4][j] += xv[j] * m1.x;
            acc[5][j] += xv[j] * m1.y;
            acc[6][j] += xv[j] * m1.z;
            acc[7][j] += xv[j] * m1.w;
        }
    }

#pragma unroll
    for (int i = 0; i < 8; ++i) {
        size_t baseo = (size_t)(b * 64 + 8 * dq + i) * TIME_N + t0 + tq;
#pragma unroll
        for (int j = 0; j < 4; ++j) out[baseo + 32 * j] = acc[i][j];
    }
}

// ---------------------------------------------------------------------------
// Kernel 2: fused STFT -> per-bin frame recursion -> iSTFT -> OLA -> tanh.
// (unchanged from R17: in-place wave-private radix-16 FFTs on packed vf2,
// FCHUNK=16, 16 barrier regions, fused conj-pair scan, hoisted twiddle
// powers, stage-level frame interleave.)
// ---------------------------------------------------------------------------
__device__ __forceinline__ int P(int i) { return i + (i >> 4); }   // pad-16
#define BUFSZ 1088   // P(1023) = 1086

__device__ __forceinline__ vf2 cmul(vf2 a, vf2 b) {
    const vf2 ns = {-1.f, 1.f};
    return a.xx * b + ns * (a.yy * b.yx);
}
// a * conj(w)
__device__ __forceinline__ vf2 cmulc(vf2 a, vf2 w) {
    const vf2 ns = {1.f, -1.f};
    return w.xx * a + ns * (w.yy * a.yx);
}
template<int SGN>
__device__ __forceinline__ vf2 cmul_s(vf2 a, vf2 w) {
    if (SGN < 0) return cmul(a, w);
    else         return cmulc(a, w);
}

// tanh(x) = 1 - 2/(e^{2x}+1); saturates correctly at +-1 (e->inf or 0).
__device__ __forceinline__ float ftanh(float x) {
    float e = __expf(2.0f * x);
    return 1.0f - 2.0f * __builtin_amdgcn_rcpf(e + 1.0f);
}

struct Tw16 { vf2 w1, w2, w3, w4, w8, w12; };

// DFT4 (no twiddles): X_m with kernel e^{SGN*2pi i mk/4}
template<int SGN>
__device__ __forceinline__ void dft4(vf2 x0, vf2 x1, vf2 x2, vf2 x3,
                                     vf2& y0, vf2& y1, vf2& y2, vf2& y3) {
    const vf2 nsj = {-(float)SGN, (float)SGN};
    vf2 apc = x0 + x2, amc = x0 - x2;
    vf2 bpd = x1 + x3, bmd = x1 - x3;
    vf2 sj  = nsj * bmd.yx;            // SGN*j*(x1-x3)
    y0 = apc + bpd;
    y1 = amc + sj;
    y2 = apc - bpd;
    y3 = amc - sj;
}

// z[j] = DFT16(x)[j] * w^j; w powers precomputed (fwd values; inv via conj).
template<int SGN>
__device__ __forceinline__ void dft16_tw(const vf2 (&x)[16], const Tw16& tw,
                                         vf2 (&z)[16]) {
    const float S = (float)SGN;
    const vf2 K1 = { 0.9238795325112867f, S * 0.3826834323650898f};
    const vf2 K2 = { 0.7071067811865476f, S * 0.7071067811865476f};
    const vf2 K3 = { 0.3826834323650898f, S * 0.9238795325112867f};
    const vf2 K6 = {-0.7071067811865476f, S * 0.7071067811865476f};
    const vf2 K9 = {-0.9238795325112867f, -S * 0.3826834323650898f};
    const vf2 nsj = {-S, S};
    vf2 u[16];
    {   // layer 1: DFT4 over x[i+4m] -> u[4i+m], internal twiddle K[(i*m)&15]
        vf2 y0, y1, y2, y3;
        dft4<SGN>(x[0], x[4], x[8],  x[12], y0, y1, y2, y3);
        u[0]=y0; u[1]=y1; u[2]=y2; u[3]=y3;
        dft4<SGN>(x[1], x[5], x[9],  x[13], y0, y1, y2, y3);
        u[4]=y0; u[5]=cmul(y1,K1); u[6]=cmul(y2,K2); u[7]=cmul(y3,K3);
        dft4<SGN>(x[2], x[6], x[10], x[14], y0, y1, y2, y3);
        u[8]=y0; u[9]=cmul(y1,K2);
        u[10]= nsj * y2.yx;                           // * e^{SGN*pi i/2}
        u[11]=cmul(y3,K6);
        dft4<SGN>(x[3], x[7], x[11], x[15], y0, y1, y2, y3);
        u[12]=y0; u[13]=cmul(y1,K3); u[14]=cmul(y2,K6); u[15]=cmul(y3,K9);
    }
#pragma unroll
    for (int i = 0; i < 4; ++i) {
        vf2 y0, y1, y2, y3;
        dft4<SGN>(u[i], u[i+4], u[i+8], u[i+12], y0, y1, y2, y3);
        vf2 t1 = cmul_s<SGN>(y1, tw.w4);
        vf2 t2 = cmul_s<SGN>(y2, tw.w8);
        vf2 t3 = cmul_s<SGN>(y3, tw.w12);
        if (i == 0) { z[0] = y0; z[4] = t1; z[8] = t2; z[12] = t3; }
        else {
            vf2 wl = (i == 1) ? tw.w1 : ((i == 2) ? tw.w2 : tw.w3);
            z[i]      = cmul_s<SGN>(y0, wl);
            z[i + 4]  = cmul_s<SGN>(t1, wl);
            z[i + 8]  = cmul_s<SGN>(t2, wl);
            z[i + 12] = cmul_s<SGN>(t3, wl);
        }
    }
}

// IN-PLACE LDS radix-16 Stockham stage (wave-private). lane in [0,64).
template<int SGN, int S>
__device__ __forceinline__ void stage16_ip(vf2* __restrict__ b,
                                           const Tw16& tw, int lane) {
    const int p = lane / S;
    const int q = lane - p * S;
    vf2 x[16];
#pragma unroll
    for (int m = 0; m < 16; ++m) x[m] = b[P(lane + 64 * m)];
    vf2 z[16];
    dft16_tw<SGN>(x, tw, z);
#pragma unroll
    for (int m = 0; m < 16; ++m) b[P(q + 16 * S * p + S * m)] = z[m];
}

// Final radix-4 stage (s=256): twiddle-free, in-place (wave-private).
template<int SGN>
__device__ __forceinline__ void stage4_ip(vf2* __restrict__ buf, int lt) {
#pragma unroll
    for (int r = 0; r < 4; ++r) {
        int i = lt + 64 * r;
        vf2 a = buf[P(i)], b = buf[P(i + 256)], c = buf[P(i + 512)], d = buf[P(i + 768)];
        vf2 y0, y1, y2, y3;
        dft4<SGN>(a, b, c, d, y0, y1, y2, y3);
        buf[P(i)]       = y0;
        buf[P(i + 256)] = y1;
        buf[P(i + 512)] = y2;
        buf[P(i + 768)] = y3;
    }
}

// Forward stage A (s=1): fused global load + Hann window + DFT16 -> LDS.
__device__ __forceinline__ void fwd_stageA(const float* __restrict__ io,
                                           size_t base, int tb,
                                           const vf2* __restrict__ win2,
                                           const Tw16& twA,
                                           vf2* __restrict__ dst, int lt) {
    const vf2 one = {1.f, 1.f};
    vf2 x[16];
#pragma unroll
    for (int m = 0; m < 16; ++m) {
        int n = lt + 64 * m;               // complex slot 0..1023
        int t = tb + 2 * n;
        vf2 v = {0.f, 0.f};
        if (t < TIME_N)
            v = *reinterpret_cast<const vf2*>(io + base + t);
        vf2 wv;
        if (m < 8) wv = win2[n];
        else       wv = one - win2[n - 512];
        x[m] = v * wv;
    }
    vf2 z[16];
    dft16_tw<-1>(x, twA, z);
#pragma unroll
    for (int m = 0; m < 16; ++m) dst[P(16 * lt + m)] = z[m];
}

__global__ __launch_bounds__(512) void stft_chain_kernel(
    const float* __restrict__ transfer,
    const float* __restrict__ gainp,
    float* __restrict__ io)
{
    __shared__ vf2 buf[FCHUNK][BUFSZ];          // 139.3 KB (single, in-place)
    __shared__ vf2 tailbuf[2][512];             // 8 KB raw chunk-crossing tail
    __shared__ vf2 twl[64];                     // 0.5 KB e^{-2pi i j/1024}
    __shared__ vf2 win2[512];                   // 4 KB (win(2m), win(2m+1))

    const int bd  = blockIdx.x;        // 0..255
    const int d   = bd & 63;
    const int tid = threadIdx.x;       // 0..511
    const int lf  = tid >> 6;          // wave id (0..7); owns frames 2lf, 2lf+1
    const int lt  = tid & 63;          // lane within wave
    const float g = gainp[0];
    const size_t base = (size_t)bd * TIME_N;
    const float PI  = 3.14159265358979323846f;
    const float PI2 = 6.2831853071795864769f;
    const float inv = 1.0f / 1024.0f;
    const vf2 cj = {1.f, -1.f};
    const vf2 nm = {-1.f, 1.f};
    const vf2 one = {1.f, 1.f};

    // --- persistent per-thread state: bin pair (tid, 1024-tid) + 512 on t0 ---
    const int kb = (tid == 0) ? 1024 : 1024 - tid;
    const float T0 = transfer[(size_t)d * NBINS + tid];
    const float T1 = transfer[(size_t)d * NBINS + kb];
    const float T5 = (tid == 0) ? transfer[(size_t)d * NBINS + 512] : 0.f;
    vf2 C0 = {0.f, 0.f};
    vf2 C1 = {0.f, 0.f};
    vf2 C5 = {0.f, 0.f};
    float sHt, cHt; __sincosf((PI / HALFN) * (float)tid, &sHt, &cHt);
    const vf2 e2m = {cHt, -sHt};       // e^{-i pi k/1024}
    const vf2 e2p = {cHt,  sHt};       // e^{+i pi m/1024}

    // one-time LDS init
    tailbuf[0][tid] = (vf2){0.f, 0.f};
    tailbuf[1][tid] = (vf2){0.f, 0.f};
    if (tid < 64) {
        float s_, c_; __sincosf(-(PI2 / 1024.0f) * (float)tid, &s_, &c_);
        twl[tid] = (vf2){c_, s_};
    }
    {
        const float cd = __cosf(PI / 1024.0f);
        const float sd = __sinf(PI / 1024.0f);
        float s0, c0; __sincosf((PI / 512.0f) * (float)tid, &s0, &c0);
        float c1 = c0 * cd - s0 * sd;
        win2[tid] = (vf2){0.5f - 0.5f * c0, 0.5f - 0.5f * c1};
    }
    __syncthreads();

    // --- hoisted external twiddle powers (per-lane constants, fwd values) ---
    Tw16 twA, twB;
    {
        vf2 a = twl[lt];                  // stage shape S=1 base
        twA.w1 = a;
        twA.w2 = cmul(a, a);
        twA.w3 = cmul(twA.w2, a);
        twA.w4 = cmul(twA.w2, twA.w2);
        twA.w8 = cmul(twA.w4, twA.w4);
        twA.w12= cmul(twA.w8, twA.w4);
        vf2 b = twl[16 * (lt >> 4)];      // stage shape S=16 base
        twB.w1 = b;
        twB.w2 = cmul(b, b);
        twB.w3 = cmul(twB.w2, b);
        twB.w4 = cmul(twB.w2, twB.w2);
        twB.w8 = cmul(twB.w4, twB.w4);
        twB.w12= cmul(twB.w8, twB.w4);
    }

    for (int ch = 0; ch < NCHUNK; ++ch) {
        const int par = ch & 1;
        const int f0  = 2 * lf;
        const int f1  = 2 * lf + 1;
        const int tb0 = (ch * FCHUNK + f0) * HALFN;
        const int tb1 = tb0 + HALFN;

        // ---- forward FFTs, stage-interleaved across the two owned frames ----
        fwd_stageA(io, base, tb0, win2, twA, &buf[f0][0], lt);
        fwd_stageA(io, base, tb1, win2, twA, &buf[f1][0], lt);
        stage16_ip<-1, 16>(&buf[f0][0], twB, lt);
        stage16_ip<-1, 16>(&buf[f1][0], twB, lt);
        stage4_ip<-1>(&buf[f0][0], lt);
        stage4_ip<-1>(&buf[f1][0], lt);
        __syncthreads();   // #1: all frames' Z ready

        // ---- FUSED rfft-post + scan + irfft-pre, in-place (16 frames) ----
        {
            vf2 Zk = buf[0][P(tid)];
            vf2 Zn = buf[0][P((HALFN - tid) & (HALFN - 1))];
#pragma unroll 2
            for (int f = 0; f < FCHUNK; ++f) {
                vf2 Zk_n, Zn_n;
                if (f < FCHUNK - 1) {
                    Zk_n = buf[f + 1][P(tid)];
                    Zn_n = buf[f + 1][P((HALFN - tid) & (HALFN - 1))];
                }
                vf2 Fe = 0.5f * (Zk + cj * Zn);        // (Zk.x+Zn.x, Zk.y-Zn.y)/2
                vf2 Fo = 0.5f * (cj * Zk.yx + Zn.yx);  // (Zk.y+Zn.y, -(Zk.x-Zn.x))/2
                vf2 U  = cmul(e2m, Fo);
                C0 = (Fe + U + C0) * T0;
                C1 = (cj * (Fe - U) + C1) * T1;
                vf2 Fe2 = 0.5f * (C0 + cj * C1);
                vf2 num = 0.5f * (C0 - cj * C1);
                vf2 Fo2 = cmul(e2p, num);
                buf[f][P(tid)] = Fe2 + nm * Fo2.yx;    // (Fe2.x-Fo2.y, Fe2.y+Fo2.x)
                if (tid != 0) {
                    buf[f][P(HALFN - tid)] = cj * Fe2 + Fo2.yx;
                } else {
                    vf2 Z5 = buf[f][P(512)];
                    C5 = (cj * Z5 + C5) * T5;
                    buf[f][P(512)] = cj * C5;
                }
                Zk = Zk_n; Zn = Zn_n;
            }
        }
        __syncthreads();   // #2: all Z' ready

        // ---- inverse FFTs, stage-interleaved across the two owned frames ----
        stage16_ip<1, 1>(&buf[f0][0], twA, lt);
        stage16_ip<1, 1>(&buf[f1][0], twA, lt);
        stage16_ip<1, 16>(&buf[f0][0], twB, lt);
        stage16_ip<1, 16>(&buf[f1][0], twB, lt);
        stage4_ip<1>(&buf[f0][0], lt);
        stage4_ip<1>(&buf[f1][0], lt);

        // ---- wave 7: stash raw second half of frame 15 for next chunk ----
        if (lf == 7) {
#pragma unroll 2
            for (int j = 0; j < 8; ++j) {
                int m = lt + 64 * j;                   // 0..511
                tailbuf[par][m] = buf[FCHUNK - 1][P(m + 512)];
            }
        }
        __syncthreads();   // #3: inverse results + tail ready

        // ---- phase B: OLA + gain + tanh, both frames ----
        {
#pragma unroll 2
            for (int j = 0; j < 8; ++j) {
                int m = lt + 64 * j;                   // 0..511
                vf2 z0  = buf[f0][P(m)];
                vf2 zp0 = (f0 == 0) ? tailbuf[par ^ 1][m]
                                    : buf[f0 - 1][P(m + 512)];
                vf2 z1  = buf[f1][P(m)];
                vf2 zp1 = buf[f0][P(m + 512)];
                vf2 wf = win2[m];
                vf2 y0v = (z0 * wf + zp0 * (one - wf)) * inv;
                vf2 y1v = (z1 * wf + zp1 * (one - wf)) * inv;
                vf2 o0 = {ftanh(g * y0v.x), ftanh(g * y0v.y)};
                vf2 o1 = {ftanh(g * y1v.x), ftanh(g * y1v.y)};
                *reinterpret_cast<vf2*>(io + base + tb0 + 2 * m) = o0;
                *reinterpret_cast<vf2*>(io + base + tb1 + 2 * m) = o1;
            }
        }
        __syncthreads();   // #4: protect buffers before next chunk's overwrite
    }
}

// ---------------------------------------------------------------------------
extern "C" void kernel_launch(void* const* d_in, const int* in_sizes, int n_in,
                              void* d_out, int out_size, void* d_ws, size_t ws_size,
                              hipStream_t stream) {
    const float* x        = (const float*)d_in[0];   // (4,64,65536)
    const float* transfer = (const float*)d_in[1];   // (64,1025)
    const float* mixer    = (const float*)d_in[2];   // (64,64)
    const float* gain     = (const float*)d_in[3];   // (1,)
    float* out = (float*)d_out;                      // (4,64,65536)

    dim3 g1(TIME_N / TT, 4);
    mix_kernel<<<g1, 256, 0, stream>>>(x, mixer, out);

    stft_chain_kernel<<<256, 512, 0, stream>>>(transfer, gain, out);
}

// Round 19
// 115.059 us; speedup vs baseline: 1.1008x; 1.1008x over previous
//
#include <hip/hip_runtime.h>
#include <math.h>

#define TIME_N 65536
#define HALFN  1024
#define NBINS  1025
#define NFRAMES 64
#define FCHUNK 16
#define NCHUNK (NFRAMES / FCHUNK)   // 4

typedef float vf2 __attribute__((ext_vector_type(2)));

// ---------------------------------------------------------------------------
// Kernel 1: channel mixing  out[b,d,t] = sum_c x[b,c,t] * M[c,d]
// R17 structure (LDS-staged M + x tile, thread owns 8d x 4 consecutive t,
// float4 stores) with the 8 scalar Ml reads replaced by 2 ds_read_b128
// broadcasts -> 3 LDS instructions per c-iteration (was 9).
// ---------------------------------------------------------------------------
#define TT 128
__global__ __launch_bounds__(256) void mix_kernel(const float* __restrict__ x,
                                                  const float* __restrict__ M,
                                                  float* __restrict__ out) {
    __shared__ float Ml[64 * 64];
    __shared__ float xt[64][136];
    const int b   = blockIdx.y;
    const int t0  = blockIdx.x * TT;
    const int tid = threadIdx.x;

    // Ml fill: 1024 float4 / 256 threads = 4 each
    for (int i = tid; i < 1024; i += 256)
        *reinterpret_cast<float4*>(&Ml[4 * i]) =
            *reinterpret_cast<const float4*>(M + 4 * i);

    // x tile fill: 64 rows x 128 floats = 2048 float4 / 256 threads = 8 each
    for (int r = 0; r < 8; ++r) {
        int fi = tid + r * 256;
        int c  = fi >> 5;
        int t4 = fi & 31;
        float4 v = *reinterpret_cast<const float4*>(
            x + (size_t)(b * 64 + c) * TIME_N + t0 + t4 * 4);
        *reinterpret_cast<float4*>(&xt[c][t4 * 4]) = v;
    }
    __syncthreads();

    const int dq = tid >> 5;   // 0..7  -> d block of 8
    const int tq = tid & 31;   // 4 consecutive t at 4*tq

    float acc[8][4];
#pragma unroll
    for (int i = 0; i < 8; ++i)
#pragma unroll
        for (int j = 0; j < 4; ++j) acc[i][j] = 0.f;

#pragma unroll 4
    for (int c = 0; c < 64; ++c) {
        float4 xv = *reinterpret_cast<const float4*>(&xt[c][4 * tq]);
        float4 m0 = *reinterpret_cast<const float4*>(&Ml[c * 64 + 8 * dq]);
        float4 m1 = *reinterpret_cast<const float4*>(&Ml[c * 64 + 8 * dq + 4]);
        acc[0][0] += xv.x * m0.x; acc[0][1] += xv.y * m0.x;
        acc[0][2] += xv.z * m0.x; acc[0][3] += xv.w * m0.x;
        acc[1][0] += xv.x * m0.y; acc[1][1] += xv.y * m0.y;
        acc[1][2] += xv.z * m0.y; acc[1][3] += xv.w * m0.y;
        acc[2][0] += xv.x * m0.z; acc[2][1] += xv.y * m0.z;
        acc[2][2] += xv.z * m0.z; acc[2][3] += xv.w * m0.z;
        acc[3][0] += xv.x * m0.w; acc[3][1] += xv.y * m0.w;
        acc[3][2] += xv.z * m0.w; acc[3][3] += xv.w * m0.w;
        acc[4][0] += xv.x * m1.x; acc[4][1] += xv.y * m1.x;
        acc[4][2] += xv.z * m1.x; acc[4][3] += xv.w * m1.x;
        acc[5][0] += xv.x * m1.y; acc[5][1] += xv.y * m1.y;
        acc[5][2] += xv.z * m1.y; acc[5][3] += xv.w * m1.y;
        acc[6][0] += xv.x * m1.z; acc[6][1] += xv.y * m1.z;
        acc[6][2] += xv.z * m1.z; acc[6][3] += xv.w * m1.z;
        acc[7][0] += xv.x * m1.w; acc[7][1] += xv.y * m1.w;
        acc[7][2] += xv.z * m1.w; acc[7][3] += xv.w * m1.w;
    }

#pragma unroll
    for (int i = 0; i < 8; ++i) {
        int d = dq * 8 + i;
        size_t baseo = (size_t)(b * 64 + d) * TIME_N + t0 + 4 * tq;
        float4 o = make_float4(acc[i][0], acc[i][1], acc[i][2], acc[i][3]);
        *reinterpret_cast<float4*>(out + baseo) = o;
    }
}

// ---------------------------------------------------------------------------
// Kernel 2: fused STFT -> per-bin frame recursion -> iSTFT -> OLA -> tanh.
// (unchanged from R17: in-place wave-private radix-16 FFTs on packed vf2,
// FCHUNK=16, 16 barrier regions, fused conj-pair scan, hoisted twiddle
// powers, stage-level frame interleave.)
// ---------------------------------------------------------------------------
__device__ __forceinline__ int P(int i) { return i + (i >> 4); }   // pad-16
#define BUFSZ 1088   // P(1023) = 1086

__device__ __forceinline__ vf2 cmul(vf2 a, vf2 b) {
    const vf2 ns = {-1.f, 1.f};
    return a.xx * b + ns * (a.yy * b.yx);
}
// a * conj(w)
__device__ __forceinline__ vf2 cmulc(vf2 a, vf2 w) {
    const vf2 ns = {1.f, -1.f};
    return w.xx * a + ns * (w.yy * a.yx);
}
template<int SGN>
__device__ __forceinline__ vf2 cmul_s(vf2 a, vf2 w) {
    if (SGN < 0) return cmul(a, w);
    else         return cmulc(a, w);
}

// tanh(x) = 1 - 2/(e^{2x}+1); saturates correctly at +-1 (e->inf or 0).
__device__ __forceinline__ float ftanh(float x) {
    float e = __expf(2.0f * x);
    return 1.0f - 2.0f * __builtin_amdgcn_rcpf(e + 1.0f);
}

struct Tw16 { vf2 w1, w2, w3, w4, w8, w12; };

// DFT4 (no twiddles): X_m with kernel e^{SGN*2pi i mk/4}
template<int SGN>
__device__ __forceinline__ void dft4(vf2 x0, vf2 x1, vf2 x2, vf2 x3,
                                     vf2& y0, vf2& y1, vf2& y2, vf2& y3) {
    const vf2 nsj = {-(float)SGN, (float)SGN};
    vf2 apc = x0 + x2, amc = x0 - x2;
    vf2 bpd = x1 + x3, bmd = x1 - x3;
    vf2 sj  = nsj * bmd.yx;            // SGN*j*(x1-x3)
    y0 = apc + bpd;
    y1 = amc + sj;
    y2 = apc - bpd;
    y3 = amc - sj;
}

// z[j] = DFT16(x)[j] * w^j; w powers precomputed (fwd values; inv via conj).
template<int SGN>
__device__ __forceinline__ void dft16_tw(const vf2 (&x)[16], const Tw16& tw,
                                         vf2 (&z)[16]) {
    const float S = (float)SGN;
    const vf2 K1 = { 0.9238795325112867f, S * 0.3826834323650898f};
    const vf2 K2 = { 0.7071067811865476f, S * 0.7071067811865476f};
    const vf2 K3 = { 0.3826834323650898f, S * 0.9238795325112867f};
    const vf2 K6 = {-0.7071067811865476f, S * 0.7071067811865476f};
    const vf2 K9 = {-0.9238795325112867f, -S * 0.3826834323650898f};
    const vf2 nsj = {-S, S};
    vf2 u[16];
    {   // layer 1: DFT4 over x[i+4m] -> u[4i+m], internal twiddle K[(i*m)&15]
        vf2 y0, y1, y2, y3;
        dft4<SGN>(x[0], x[4], x[8],  x[12], y0, y1, y2, y3);
        u[0]=y0; u[1]=y1; u[2]=y2; u[3]=y3;
        dft4<SGN>(x[1], x[5], x[9],  x[13], y0, y1, y2, y3);
        u[4]=y0; u[5]=cmul(y1,K1); u[6]=cmul(y2,K2); u[7]=cmul(y3,K3);
        dft4<SGN>(x[2], x[6], x[10], x[14], y0, y1, y2, y3);
        u[8]=y0; u[9]=cmul(y1,K2);
        u[10]= nsj * y2.yx;                           // * e^{SGN*pi i/2}
        u[11]=cmul(y3,K6);
        dft4<SGN>(x[3], x[7], x[11], x[15], y0, y1, y2, y3);
        u[12]=y0; u[13]=cmul(y1,K3); u[14]=cmul(y2,K6); u[15]=cmul(y3,K9);
    }
#pragma unroll
    for (int i = 0; i < 4; ++i) {
        vf2 y0, y1, y2, y3;
        dft4<SGN>(u[i], u[i+4], u[i+8], u[i+12], y0, y1, y2, y3);
        vf2 t1 = cmul_s<SGN>(y1, tw.w4);
        vf2 t2 = cmul_s<SGN>(y2, tw.w8);
        vf2 t3 = cmul_s<SGN>(y3, tw.w12);
        if (i == 0) { z[0] = y0; z[4] = t1; z[8] = t2; z[12] = t3; }
        else {
            vf2 wl = (i == 1) ? tw.w1 : ((i == 2) ? tw.w2 : tw.w3);
            z[i]      = cmul_s<SGN>(y0, wl);
            z[i + 4]  = cmul_s<SGN>(t1, wl);
            z[i + 8]  = cmul_s<SGN>(t2, wl);
            z[i + 12] = cmul_s<SGN>(t3, wl);
        }
    }
}

// IN-PLACE LDS radix-16 Stockham stage (wave-private). lane in [0,64).
template<int SGN, int S>
__device__ __forceinline__ void stage16_ip(vf2* __restrict__ b,
                                           const Tw16& tw, int lane) {
    const int p = lane / S;
    const int q = lane - p * S;
    vf2 x[16];
#pragma unroll
    for (int m = 0; m < 16; ++m) x[m] = b[P(lane + 64 * m)];
    vf2 z[16];
    dft16_tw<SGN>(x, tw, z);
#pragma unroll
    for (int m = 0; m < 16; ++m) b[P(q + 16 * S * p + S * m)] = z[m];
}

// Final radix-4 stage (s=256): twiddle-free, in-place (wave-private).
template<int SGN>
__device__ __forceinline__ void stage4_ip(vf2* __restrict__ buf, int lt) {
#pragma unroll
    for (int r = 0; r < 4; ++r) {
        int i = lt + 64 * r;
        vf2 a = buf[P(i)], b = buf[P(i + 256)], c = buf[P(i + 512)], d = buf[P(i + 768)];
        vf2 y0, y1, y2, y3;
        dft4<SGN>(a, b, c, d, y0, y1, y2, y3);
        buf[P(i)]       = y0;
        buf[P(i + 256)] = y1;
        buf[P(i + 512)] = y2;
        buf[P(i + 768)] = y3;
    }
}

// Forward stage A (s=1): fused global load + Hann window + DFT16 -> LDS.
__device__ __forceinline__ void fwd_stageA(const float* __restrict__ io,
                                           size_t base, int tb,
                                           const vf2* __restrict__ win2,
                                           const Tw16& twA,
                                           vf2* __restrict__ dst, int lt) {
    const vf2 one = {1.f, 1.f};
    vf2 x[16];
#pragma unroll
    for (int m = 0; m < 16; ++m) {
        int n = lt + 64 * m;               // complex slot 0..1023
        int t = tb + 2 * n;
        vf2 v = {0.f, 0.f};
        if (t < TIME_N)
            v = *reinterpret_cast<const vf2*>(io + base + t);
        vf2 wv;
        if (m < 8) wv = win2[n];
        else       wv = one - win2[n - 512];
        x[m] = v * wv;
    }
    vf2 z[16];
    dft16_tw<-1>(x, twA, z);
#pragma unroll
    for (int m = 0; m < 16; ++m) dst[P(16 * lt + m)] = z[m];
}

__global__ __launch_bounds__(512) void stft_chain_kernel(
    const float* __restrict__ transfer,
    const float* __restrict__ gainp,
    float* __restrict__ io)
{
    __shared__ vf2 buf[FCHUNK][BUFSZ];          // 139.3 KB (single, in-place)
    __shared__ vf2 tailbuf[2][512];             // 8 KB raw chunk-crossing tail
    __shared__ vf2 twl[64];                     // 0.5 KB e^{-2pi i j/1024}
    __shared__ vf2 win2[512];                   // 4 KB (win(2m), win(2m+1))

    const int bd  = blockIdx.x;        // 0..255
    const int d   = bd & 63;
    const int tid = threadIdx.x;       // 0..511
    const int lf  = tid >> 6;          // wave id (0..7); owns frames 2lf, 2lf+1
    const int lt  = tid & 63;          // lane within wave
    const float g = gainp[0];
    const size_t base = (size_t)bd * TIME_N;
    const float PI  = 3.14159265358979323846f;
    const float PI2 = 6.2831853071795864769f;
    const float inv = 1.0f / 1024.0f;
    const vf2 cj = {1.f, -1.f};
    const vf2 nm = {-1.f, 1.f};
    const vf2 one = {1.f, 1.f};

    // --- persistent per-thread state: bin pair (tid, 1024-tid) + 512 on t0 ---
    const int kb = (tid == 0) ? 1024 : 1024 - tid;
    const float T0 = transfer[(size_t)d * NBINS + tid];
    const float T1 = transfer[(size_t)d * NBINS + kb];
    const float T5 = (tid == 0) ? transfer[(size_t)d * NBINS + 512] : 0.f;
    vf2 C0 = {0.f, 0.f};
    vf2 C1 = {0.f, 0.f};
    vf2 C5 = {0.f, 0.f};
    float sHt, cHt; __sincosf((PI / HALFN) * (float)tid, &sHt, &cHt);
    const vf2 e2m = {cHt, -sHt};       // e^{-i pi k/1024}
    const vf2 e2p = {cHt,  sHt};       // e^{+i pi m/1024}

    // one-time LDS init
    tailbuf[0][tid] = (vf2){0.f, 0.f};
    tailbuf[1][tid] = (vf2){0.f, 0.f};
    if (tid < 64) {
        float s_, c_; __sincosf(-(PI2 / 1024.0f) * (float)tid, &s_, &c_);
        twl[tid] = (vf2){c_, s_};
    }
    {
        const float cd = __cosf(PI / 1024.0f);
        const float sd = __sinf(PI / 1024.0f);
        float s0, c0; __sincosf((PI / 512.0f) * (float)tid, &s0, &c0);
        float c1 = c0 * cd - s0 * sd;
        win2[tid] = (vf2){0.5f - 0.5f * c0, 0.5f - 0.5f * c1};
    }
    __syncthreads();

    // --- hoisted external twiddle powers (per-lane constants, fwd values) ---
    Tw16 twA, twB;
    {
        vf2 a = twl[lt];                  // stage shape S=1 base
        twA.w1 = a;
        twA.w2 = cmul(a, a);
        twA.w3 = cmul(twA.w2, a);
        twA.w4 = cmul(twA.w2, twA.w2);
        twA.w8 = cmul(twA.w4, twA.w4);
        twA.w12= cmul(twA.w8, twA.w4);
        vf2 b = twl[16 * (lt >> 4)];      // stage shape S=16 base
        twB.w1 = b;
        twB.w2 = cmul(b, b);
        twB.w3 = cmul(twB.w2, b);
        twB.w4 = cmul(twB.w2, twB.w2);
        twB.w8 = cmul(twB.w4, twB.w4);
        twB.w12= cmul(twB.w8, twB.w4);
    }

    for (int ch = 0; ch < NCHUNK; ++ch) {
        const int par = ch & 1;
        const int f0  = 2 * lf;
        const int f1  = 2 * lf + 1;
        const int tb0 = (ch * FCHUNK + f0) * HALFN;
        const int tb1 = tb0 + HALFN;

        // ---- forward FFTs, stage-interleaved across the two owned frames ----
        fwd_stageA(io, base, tb0, win2, twA, &buf[f0][0], lt);
        fwd_stageA(io, base, tb1, win2, twA, &buf[f1][0], lt);
        stage16_ip<-1, 16>(&buf[f0][0], twB, lt);
        stage16_ip<-1, 16>(&buf[f1][0], twB, lt);
        stage4_ip<-1>(&buf[f0][0], lt);
        stage4_ip<-1>(&buf[f1][0], lt);
        __syncthreads();   // #1: all frames' Z ready

        // ---- FUSED rfft-post + scan + irfft-pre, in-place (16 frames) ----
        {
            vf2 Zk = buf[0][P(tid)];
            vf2 Zn = buf[0][P((HALFN - tid) & (HALFN - 1))];
#pragma unroll 2
            for (int f = 0; f < FCHUNK; ++f) {
                vf2 Zk_n, Zn_n;
                if (f < FCHUNK - 1) {
                    Zk_n = buf[f + 1][P(tid)];
                    Zn_n = buf[f + 1][P((HALFN - tid) & (HALFN - 1))];
                }
                vf2 Fe = 0.5f * (Zk + cj * Zn);        // (Zk.x+Zn.x, Zk.y-Zn.y)/2
                vf2 Fo = 0.5f * (cj * Zk.yx + Zn.yx);  // (Zk.y+Zn.y, -(Zk.x-Zn.x))/2
                vf2 U  = cmul(e2m, Fo);
                C0 = (Fe + U + C0) * T0;
                C1 = (cj * (Fe - U) + C1) * T1;
                vf2 Fe2 = 0.5f * (C0 + cj * C1);
                vf2 num = 0.5f * (C0 - cj * C1);
                vf2 Fo2 = cmul(e2p, num);
                buf[f][P(tid)] = Fe2 + nm * Fo2.yx;    // (Fe2.x-Fo2.y, Fe2.y+Fo2.x)
                if (tid != 0) {
                    buf[f][P(HALFN - tid)] = cj * Fe2 + Fo2.yx;
                } else {
                    vf2 Z5 = buf[f][P(512)];
                    C5 = (cj * Z5 + C5) * T5;
                    buf[f][P(512)] = cj * C5;
                }
                Zk = Zk_n; Zn = Zn_n;
            }
        }
        __syncthreads();   // #2: all Z' ready

        // ---- inverse FFTs, stage-interleaved across the two owned frames ----
        stage16_ip<1, 1>(&buf[f0][0], twA, lt);
        stage16_ip<1, 1>(&buf[f1][0], twA, lt);
        stage16_ip<1, 16>(&buf[f0][0], twB, lt);
        stage16_ip<1, 16>(&buf[f1][0], twB, lt);
        stage4_ip<1>(&buf[f0][0], lt);
        stage4_ip<1>(&buf[f1][0], lt);

        // ---- wave 7: stash raw second half of frame 15 for next chunk ----
        if (lf == 7) {
#pragma unroll 2
            for (int j = 0; j < 8; ++j) {
                int m = lt + 64 * j;                   // 0..511
                tailbuf[par][m] = buf[FCHUNK - 1][P(m + 512)];
            }
        }
        __syncthreads();   // #3: inverse results + tail ready

        // ---- phase B: OLA + gain + tanh, both frames ----
        {
#pragma unroll 2
            for (int j = 0; j < 8; ++j) {
                int m = lt + 64 * j;                   // 0..511
                vf2 z0  = buf[f0][P(m)];
                vf2 zp0 = (f0 == 0) ? tailbuf[par ^ 1][m]
                                    : buf[f0 - 1][P(m + 512)];
                vf2 z1  = buf[f1][P(m)];
                vf2 zp1 = buf[f0][P(m + 512)];
                vf2 wf = win2[m];
                vf2 y0v = (z0 * wf + zp0 * (one - wf)) * inv;
                vf2 y1v = (z1 * wf + zp1 * (one - wf)) * inv;
                vf2 o0 = {ftanh(g * y0v.x), ftanh(g * y0v.y)};
                vf2 o1 = {ftanh(g * y1v.x), ftanh(g * y1v.y)};
                *reinterpret_cast<vf2*>(io + base + tb0 + 2 * m) = o0;
                *reinterpret_cast<vf2*>(io + base + tb1 + 2 * m) = o1;
            }
        }
        __syncthreads();   // #4: protect buffers before next chunk's overwrite
    }
}

// ---------------------------------------------------------------------------
extern "C" void kernel_launch(void* const* d_in, const int* in_sizes, int n_in,
                              void* d_out, int out_size, void* d_ws, size_t ws_size,
                              hipStream_t stream) {
    const float* x        = (const float*)d_in[0];   // (4,64,65536)
    const float* transfer = (const float*)d_in[1];   // (64,1025)
    const float* mixer    = (const float*)d_in[2];   // (64,64)
    const float* gain     = (const float*)d_in[3];   // (1,)
    float* out = (float*)d_out;                      // (4,64,65536)

    dim3 g1(TIME_N / TT, 4);
    mix_kernel<<<g1, 256, 0, stream>>>(x, mixer, out);

    stft_chain_kernel<<<256, 512, 0, stream>>>(transfer, gain, out);
}

// Round 20
// 114.838 us; speedup vs baseline: 1.1029x; 1.0019x over previous
//
#include <hip/hip_runtime.h>
#include <math.h>

#define TIME_N 65536
#define HALFN  1024
#define NBINS  1025
#define NFRAMES 64
#define FCHUNK 16
#define NCHUNK (NFRAMES / FCHUNK)   // 4

typedef float vf2 __attribute__((ext_vector_type(2)));

// ---------------------------------------------------------------------------
// Kernel 1: channel mixing  out[b,d,t] = sum_c x[b,c,t] * M[c,d]
// v3: wave-uniform d-groups -> M rows load via s_load into SGPRs (scalar
// K$-resident, no LDS/VMEM vector traffic for M). 4 waves x 16 d; lane owns
// 2 consecutive t. LDS = xt only (33.8 KB) -> 4 blocks/CU; grid 2048 /
// 1024 resident = exactly 2 rounds. Inner loop: 1 LDS float2 + 4 s_load
// + 32 FMA (SGPR broadcast operands).
// ---------------------------------------------------------------------------
#define TT 128
__global__ __launch_bounds__(256) void mix_kernel(const float* __restrict__ x,
                                                  const float* __restrict__ M,
                                                  float* __restrict__ out) {
    __shared__ float xt[64][132];   // 33.8 KB; rows 528B (16B-aligned)
    const int b   = blockIdx.y;
    const int t0  = blockIdx.x * TT;
    const int tid = threadIdx.x;

    // x tile fill: 64 rows x 128 floats = 2048 float4 / 256 threads = 8 each
    for (int r = 0; r < 8; ++r) {
        int fi = tid + r * 256;
        int c  = fi >> 5;
        int t4 = fi & 31;
        float4 v = *reinterpret_cast<const float4*>(
            x + (size_t)(b * 64 + c) * TIME_N + t0 + t4 * 4);
        *reinterpret_cast<float4*>(&xt[c][t4 * 4]) = v;
    }
    __syncthreads();

    const int l = tid & 63;                         // lane: 2 t at 2l
    // wave-uniform d-group base (forced scalar)
    const int wbase = __builtin_amdgcn_readfirstlane(16 * (tid >> 6));

    vf2 acc[16];
#pragma unroll
    for (int i = 0; i < 16; ++i) acc[i] = (vf2){0.f, 0.f};

#pragma unroll 4
    for (int c = 0; c < 64; ++c) {
        vf2 xv = *reinterpret_cast<const vf2*>(&xt[c][2 * l]);
        const float* Mp = M + c * 64 + wbase;       // uniform -> s_load
        float4 m0 = *reinterpret_cast<const float4*>(Mp);
        float4 m1 = *reinterpret_cast<const float4*>(Mp + 4);
        float4 m2 = *reinterpret_cast<const float4*>(Mp + 8);
        float4 m3 = *reinterpret_cast<const float4*>(Mp + 12);
        acc[0]  += xv * m0.x;  acc[1]  += xv * m0.y;
        acc[2]  += xv * m0.z;  acc[3]  += xv * m0.w;
        acc[4]  += xv * m1.x;  acc[5]  += xv * m1.y;
        acc[6]  += xv * m1.z;  acc[7]  += xv * m1.w;
        acc[8]  += xv * m2.x;  acc[9]  += xv * m2.y;
        acc[10] += xv * m2.z;  acc[11] += xv * m2.w;
        acc[12] += xv * m3.x;  acc[13] += xv * m3.y;
        acc[14] += xv * m3.z;  acc[15] += xv * m3.w;
    }

#pragma unroll
    for (int i = 0; i < 16; ++i) {
        int d = wbase + i;
        size_t baseo = (size_t)(b * 64 + d) * TIME_N + t0 + 2 * l;
        *reinterpret_cast<vf2*>(out + baseo) = acc[i];
    }
}

// ---------------------------------------------------------------------------
// Kernel 2: fused STFT -> per-bin frame recursion -> iSTFT -> OLA -> tanh.
// (unchanged from R17/R19: in-place wave-private radix-16 FFTs on packed vf2,
// FCHUNK=16, 16 barrier regions, fused conj-pair scan, hoisted twiddle
// powers, stage-level frame interleave.)
// ---------------------------------------------------------------------------
__device__ __forceinline__ int P(int i) { return i + (i >> 4); }   // pad-16
#define BUFSZ 1088   // P(1023) = 1086

__device__ __forceinline__ vf2 cmul(vf2 a, vf2 b) {
    const vf2 ns = {-1.f, 1.f};
    return a.xx * b + ns * (a.yy * b.yx);
}
// a * conj(w)
__device__ __forceinline__ vf2 cmulc(vf2 a, vf2 w) {
    const vf2 ns = {1.f, -1.f};
    return w.xx * a + ns * (w.yy * a.yx);
}
template<int SGN>
__device__ __forceinline__ vf2 cmul_s(vf2 a, vf2 w) {
    if (SGN < 0) return cmul(a, w);
    else         return cmulc(a, w);
}

// tanh(x) = 1 - 2/(e^{2x}+1); saturates correctly at +-1 (e->inf or 0).
__device__ __forceinline__ float ftanh(float x) {
    float e = __expf(2.0f * x);
    return 1.0f - 2.0f * __builtin_amdgcn_rcpf(e + 1.0f);
}

struct Tw16 { vf2 w1, w2, w3, w4, w8, w12; };

// DFT4 (no twiddles): X_m with kernel e^{SGN*2pi i mk/4}
template<int SGN>
__device__ __forceinline__ void dft4(vf2 x0, vf2 x1, vf2 x2, vf2 x3,
                                     vf2& y0, vf2& y1, vf2& y2, vf2& y3) {
    const vf2 nsj = {-(float)SGN, (float)SGN};
    vf2 apc = x0 + x2, amc = x0 - x2;
    vf2 bpd = x1 + x3, bmd = x1 - x3;
    vf2 sj  = nsj * bmd.yx;            // SGN*j*(x1-x3)
    y0 = apc + bpd;
    y1 = amc + sj;
    y2 = apc - bpd;
    y3 = amc - sj;
}

// z[j] = DFT16(x)[j] * w^j; w powers precomputed (fwd values; inv via conj).
template<int SGN>
__device__ __forceinline__ void dft16_tw(const vf2 (&x)[16], const Tw16& tw,
                                         vf2 (&z)[16]) {
    const float S = (float)SGN;
    const vf2 K1 = { 0.9238795325112867f, S * 0.3826834323650898f};
    const vf2 K2 = { 0.7071067811865476f, S * 0.7071067811865476f};
    const vf2 K3 = { 0.3826834323650898f, S * 0.9238795325112867f};
    const vf2 K6 = {-0.7071067811865476f, S * 0.7071067811865476f};
    const vf2 K9 = {-0.9238795325112867f, -S * 0.3826834323650898f};
    const vf2 nsj = {-S, S};
    vf2 u[16];
    {   // layer 1: DFT4 over x[i+4m] -> u[4i+m], internal twiddle K[(i*m)&15]
        vf2 y0, y1, y2, y3;
        dft4<SGN>(x[0], x[4], x[8],  x[12], y0, y1, y2, y3);
        u[0]=y0; u[1]=y1; u[2]=y2; u[3]=y3;
        dft4<SGN>(x[1], x[5], x[9],  x[13], y0, y1, y2, y3);
        u[4]=y0; u[5]=cmul(y1,K1); u[6]=cmul(y2,K2); u[7]=cmul(y3,K3);
        dft4<SGN>(x[2], x[6], x[10], x[14], y0, y1, y2, y3);
        u[8]=y0; u[9]=cmul(y1,K2);
        u[10]= nsj * y2.yx;                           // * e^{SGN*pi i/2}
        u[11]=cmul(y3,K6);
        dft4<SGN>(x[3], x[7], x[11], x[15], y0, y1, y2, y3);
        u[12]=y0; u[13]=cmul(y1,K3); u[14]=cmul(y2,K6); u[15]=cmul(y3,K9);
    }
#pragma unroll
    for (int i = 0; i < 4; ++i) {
        vf2 y0, y1, y2, y3;
        dft4<SGN>(u[i], u[i+4], u[i+8], u[i+12], y0, y1, y2, y3);
        vf2 t1 = cmul_s<SGN>(y1, tw.w4);
        vf2 t2 = cmul_s<SGN>(y2, tw.w8);
        vf2 t3 = cmul_s<SGN>(y3, tw.w12);
        if (i == 0) { z[0] = y0; z[4] = t1; z[8] = t2; z[12] = t3; }
        else {
            vf2 wl = (i == 1) ? tw.w1 : ((i == 2) ? tw.w2 : tw.w3);
            z[i]      = cmul_s<SGN>(y0, wl);
            z[i + 4]  = cmul_s<SGN>(t1, wl);
            z[i + 8]  = cmul_s<SGN>(t2, wl);
            z[i + 12] = cmul_s<SGN>(t3, wl);
        }
    }
}

// IN-PLACE LDS radix-16 Stockham stage (wave-private). lane in [0,64).
template<int SGN, int S>
__device__ __forceinline__ void stage16_ip(vf2* __restrict__ b,
                                           const Tw16& tw, int lane) {
    const int p = lane / S;
    const int q = lane - p * S;
    vf2 x[16];
#pragma unroll
    for (int m = 0; m < 16; ++m) x[m] = b[P(lane + 64 * m)];
    vf2 z[16];
    dft16_tw<SGN>(x, tw, z);
#pragma unroll
    for (int m = 0; m < 16; ++m) b[P(q + 16 * S * p + S * m)] = z[m];
}

// Final radix-4 stage (s=256): twiddle-free, in-place (wave-private).
template<int SGN>
__device__ __forceinline__ void stage4_ip(vf2* __restrict__ buf, int lt) {
#pragma unroll
    for (int r = 0; r < 4; ++r) {
        int i = lt + 64 * r;
        vf2 a = buf[P(i)], b = buf[P(i + 256)], c = buf[P(i + 512)], d = buf[P(i + 768)];
        vf2 y0, y1, y2, y3;
        dft4<SGN>(a, b, c, d, y0, y1, y2, y3);
        buf[P(i)]       = y0;
        buf[P(i + 256)] = y1;
        buf[P(i + 512)] = y2;
        buf[P(i + 768)] = y3;
    }
}

// Forward stage A (s=1): fused global load + Hann window + DFT16 -> LDS.
__device__ __forceinline__ void fwd_stageA(const float* __restrict__ io,
                                           size_t base, int tb,
                                           const vf2* __restrict__ win2,
                                           const Tw16& twA,
                                           vf2* __restrict__ dst, int lt) {
    const vf2 one = {1.f, 1.f};
    vf2 x[16];
#pragma unroll
    for (int m = 0; m < 16; ++m) {
        int n = lt + 64 * m;               // complex slot 0..1023
        int t = tb + 2 * n;
        vf2 v = {0.f, 0.f};
        if (t < TIME_N)
            v = *reinterpret_cast<const vf2*>(io + base + t);
        vf2 wv;
        if (m < 8) wv = win2[n];
        else       wv = one - win2[n - 512];
        x[m] = v * wv;
    }
    vf2 z[16];
    dft16_tw<-1>(x, twA, z);
#pragma unroll
    for (int m = 0; m < 16; ++m) dst[P(16 * lt + m)] = z[m];
}

__global__ __launch_bounds__(512) void stft_chain_kernel(
    const float* __restrict__ transfer,
    const float* __restrict__ gainp,
    float* __restrict__ io)
{
    __shared__ vf2 buf[FCHUNK][BUFSZ];          // 139.3 KB (single, in-place)
    __shared__ vf2 tailbuf[2][512];             // 8 KB raw chunk-crossing tail
    __shared__ vf2 twl[64];                     // 0.5 KB e^{-2pi i j/1024}
    __shared__ vf2 win2[512];                   // 4 KB (win(2m), win(2m+1))

    const int bd  = blockIdx.x;        // 0..255
    const int d   = bd & 63;
    const int tid = threadIdx.x;       // 0..511
    const int lf  = tid >> 6;          // wave id (0..7); owns frames 2lf, 2lf+1
    const int lt  = tid & 63;          // lane within wave
    const float g = gainp[0];
    const size_t base = (size_t)bd * TIME_N;
    const float PI  = 3.14159265358979323846f;
    const float PI2 = 6.2831853071795864769f;
    const float inv = 1.0f / 1024.0f;
    const vf2 cj = {1.f, -1.f};
    const vf2 nm = {-1.f, 1.f};
    const vf2 one = {1.f, 1.f};

    // --- persistent per-thread state: bin pair (tid, 1024-tid) + 512 on t0 ---
    const int kb = (tid == 0) ? 1024 : 1024 - tid;
    const float T0 = transfer[(size_t)d * NBINS + tid];
    const float T1 = transfer[(size_t)d * NBINS + kb];
    const float T5 = (tid == 0) ? transfer[(size_t)d * NBINS + 512] : 0.f;
    vf2 C0 = {0.f, 0.f};
    vf2 C1 = {0.f, 0.f};
    vf2 C5 = {0.f, 0.f};
    float sHt, cHt; __sincosf((PI / HALFN) * (float)tid, &sHt, &cHt);
    const vf2 e2m = {cHt, -sHt};       // e^{-i pi k/1024}
    const vf2 e2p = {cHt,  sHt};       // e^{+i pi m/1024}

    // one-time LDS init
    tailbuf[0][tid] = (vf2){0.f, 0.f};
    tailbuf[1][tid] = (vf2){0.f, 0.f};
    if (tid < 64) {
        float s_, c_; __sincosf(-(PI2 / 1024.0f) * (float)tid, &s_, &c_);
        twl[tid] = (vf2){c_, s_};
    }
    {
        const float cd = __cosf(PI / 1024.0f);
        const float sd = __sinf(PI / 1024.0f);
        float s0, c0; __sincosf((PI / 512.0f) * (float)tid, &s0, &c0);
        float c1 = c0 * cd - s0 * sd;
        win2[tid] = (vf2){0.5f - 0.5f * c0, 0.5f - 0.5f * c1};
    }
    __syncthreads();

    // --- hoisted external twiddle powers (per-lane constants, fwd values) ---
    Tw16 twA, twB;
    {
        vf2 a = twl[lt];                  // stage shape S=1 base
        twA.w1 = a;
        twA.w2 = cmul(a, a);
        twA.w3 = cmul(twA.w2, a);
        twA.w4 = cmul(twA.w2, twA.w2);
        twA.w8 = cmul(twA.w4, twA.w4);
        twA.w12= cmul(twA.w8, twA.w4);
        vf2 b = twl[16 * (lt >> 4)];      // stage shape S=16 base
        twB.w1 = b;
        twB.w2 = cmul(b, b);
        twB.w3 = cmul(twB.w2, b);
        twB.w4 = cmul(twB.w2, twB.w2);
        twB.w8 = cmul(twB.w4, twB.w4);
        twB.w12= cmul(twB.w8, twB.w4);
    }

    for (int ch = 0; ch < NCHUNK; ++ch) {
        const int par = ch & 1;
        const int f0  = 2 * lf;
        const int f1  = 2 * lf + 1;
        const int tb0 = (ch * FCHUNK + f0) * HALFN;
        const int tb1 = tb0 + HALFN;

        // ---- forward FFTs, stage-interleaved across the two owned frames ----
        fwd_stageA(io, base, tb0, win2, twA, &buf[f0][0], lt);
        fwd_stageA(io, base, tb1, win2, twA, &buf[f1][0], lt);
        stage16_ip<-1, 16>(&buf[f0][0], twB, lt);
        stage16_ip<-1, 16>(&buf[f1][0], twB, lt);
        stage4_ip<-1>(&buf[f0][0], lt);
        stage4_ip<-1>(&buf[f1][0], lt);
        __syncthreads();   // #1: all frames' Z ready

        // ---- FUSED rfft-post + scan + irfft-pre, in-place (16 frames) ----
        {
            vf2 Zk = buf[0][P(tid)];
            vf2 Zn = buf[0][P((HALFN - tid) & (HALFN - 1))];
#pragma unroll 2
            for (int f = 0; f < FCHUNK; ++f) {
                vf2 Zk_n, Zn_n;
                if (f < FCHUNK - 1) {
                    Zk_n = buf[f + 1][P(tid)];
                    Zn_n = buf[f + 1][P((HALFN - tid) & (HALFN - 1))];
                }
                vf2 Fe = 0.5f * (Zk + cj * Zn);        // (Zk.x+Zn.x, Zk.y-Zn.y)/2
                vf2 Fo = 0.5f * (cj * Zk.yx + Zn.yx);  // (Zk.y+Zn.y, -(Zk.x-Zn.x))/2
                vf2 U  = cmul(e2m, Fo);
                C0 = (Fe + U + C0) * T0;
                C1 = (cj * (Fe - U) + C1) * T1;
                vf2 Fe2 = 0.5f * (C0 + cj * C1);
                vf2 num = 0.5f * (C0 - cj * C1);
                vf2 Fo2 = cmul(e2p, num);
                buf[f][P(tid)] = Fe2 + nm * Fo2.yx;    // (Fe2.x-Fo2.y, Fe2.y+Fo2.x)
                if (tid != 0) {
                    buf[f][P(HALFN - tid)] = cj * Fe2 + Fo2.yx;
                } else {
                    vf2 Z5 = buf[f][P(512)];
                    C5 = (cj * Z5 + C5) * T5;
                    buf[f][P(512)] = cj * C5;
                }
                Zk = Zk_n; Zn = Zn_n;
            }
        }
        __syncthreads();   // #2: all Z' ready

        // ---- inverse FFTs, stage-interleaved across the two owned frames ----
        stage16_ip<1, 1>(&buf[f0][0], twA, lt);
        stage16_ip<1, 1>(&buf[f1][0], twA, lt);
        stage16_ip<1, 16>(&buf[f0][0], twB, lt);
        stage16_ip<1, 16>(&buf[f1][0], twB, lt);
        stage4_ip<1>(&buf[f0][0], lt);
        stage4_ip<1>(&buf[f1][0], lt);

        // ---- wave 7: stash raw second half of frame 15 for next chunk ----
        if (lf == 7) {
#pragma unroll 2
            for (int j = 0; j < 8; ++j) {
                int m = lt + 64 * j;                   // 0..511
                tailbuf[par][m] = buf[FCHUNK - 1][P(m + 512)];
            }
        }
        __syncthreads();   // #3: inverse results + tail ready

        // ---- phase B: OLA + gain + tanh, both frames ----
        {
#pragma unroll 2
            for (int j = 0; j < 8; ++j) {
                int m = lt + 64 * j;                   // 0..511
                vf2 z0  = buf[f0][P(m)];
                vf2 zp0 = (f0 == 0) ? tailbuf[par ^ 1][m]
                                    : buf[f0 - 1][P(m + 512)];
                vf2 z1  = buf[f1][P(m)];
                vf2 zp1 = buf[f0][P(m + 512)];
                vf2 wf = win2[m];
                vf2 y0v = (z0 * wf + zp0 * (one - wf)) * inv;
                vf2 y1v = (z1 * wf + zp1 * (one - wf)) * inv;
                vf2 o0 = {ftanh(g * y0v.x), ftanh(g * y0v.y)};
                vf2 o1 = {ftanh(g * y1v.x), ftanh(g * y1v.y)};
                *reinterpret_cast<vf2*>(io + base + tb0 + 2 * m) = o0;
                *reinterpret_cast<vf2*>(io + base + tb1 + 2 * m) = o1;
            }
        }
        __syncthreads();   // #4: protect buffers before next chunk's overwrite
    }
}

// ---------------------------------------------------------------------------
extern "C" void kernel_launch(void* const* d_in, const int* in_sizes, int n_in,
                              void* d_out, int out_size, void* d_ws, size_t ws_size,
                              hipStream_t stream) {
    const float* x        = (const float*)d_in[0];   // (4,64,65536)
    const float* transfer = (const float*)d_in[1];   // (64,1025)
    const float* mixer    = (const float*)d_in[2];   // (64,64)
    const float* gain     = (const float*)d_in[3];   // (1,)
    float* out = (float*)d_out;                      // (4,64,65536)

    dim3 g1(TIME_N / TT, 4);
    mix_kernel<<<g1, 256, 0, stream>>>(x, mixer, out);

    stft_chain_kernel<<<256, 512, 0, stream>>>(transfer, gain, out);
}

// Round 21
// 113.016 us; speedup vs baseline: 1.1207x; 1.0161x over previous
//
#include <hip/hip_runtime.h>
#include <math.h>

#define TIME_N 65536
#define HALFN  1024
#define NBINS  1025
#define NFRAMES 64
#define FCHUNK 16
#define NCHUNK (NFRAMES / FCHUNK)   // 4

typedef float vf2 __attribute__((ext_vector_type(2)));

// ---------------------------------------------------------------------------
// Kernel 1: channel mixing  out[b,d,t] = sum_c x[b,c,t] * M[c,d]
// v4: NO LDS, NO barriers. Thread owns one (b,t) column and all 64 d:
// per c-iter = 1 coalesced 4B x load + wave-uniform M row (s_load, K$)
// + 64 SGPR-broadcast FMAs into acc[64]. Every x element read exactly once.
// BW-bound pure stream (128 MB); VALU floor ~14 us, BW floor ~20 us.
// ---------------------------------------------------------------------------
__global__ __launch_bounds__(256, 4) void mix_kernel(const float* __restrict__ x,
                                                     const float* __restrict__ M,
                                                     float* __restrict__ out) {
    const int b = blockIdx.y;
    const int t = blockIdx.x * 256 + threadIdx.x;    // 0..65535
    const float* xb = x + (size_t)b * 64 * TIME_N + t;
    float* ob = out + (size_t)b * 64 * TIME_N + t;

    float acc[64];
#pragma unroll
    for (int d = 0; d < 64; ++d) acc[d] = 0.f;

#pragma unroll 2
    for (int c = 0; c < 64; ++c) {
        float xv = xb[(size_t)c * TIME_N];
        const float* Mr = M + c * 64;                // thread-uniform -> s_load
#pragma unroll
        for (int d = 0; d < 64; ++d) acc[d] += xv * Mr[d];
    }

#pragma unroll
    for (int d = 0; d < 64; ++d) ob[(size_t)d * TIME_N] = acc[d];
}

// ---------------------------------------------------------------------------
// Kernel 2: fused STFT -> per-bin frame recursion -> iSTFT -> OLA -> tanh.
// (unchanged from R17/R19/R20: in-place wave-private radix-16 FFTs on packed
// vf2, FCHUNK=16, 16 barrier regions, fused conj-pair scan, hoisted twiddle
// powers, stage-level frame interleave.)
// ---------------------------------------------------------------------------
__device__ __forceinline__ int P(int i) { return i + (i >> 4); }   // pad-16
#define BUFSZ 1088   // P(1023) = 1086

__device__ __forceinline__ vf2 cmul(vf2 a, vf2 b) {
    const vf2 ns = {-1.f, 1.f};
    return a.xx * b + ns * (a.yy * b.yx);
}
// a * conj(w)
__device__ __forceinline__ vf2 cmulc(vf2 a, vf2 w) {
    const vf2 ns = {1.f, -1.f};
    return w.xx * a + ns * (w.yy * a.yx);
}
template<int SGN>
__device__ __forceinline__ vf2 cmul_s(vf2 a, vf2 w) {
    if (SGN < 0) return cmul(a, w);
    else         return cmulc(a, w);
}

// tanh(x) = 1 - 2/(e^{2x}+1); saturates correctly at +-1 (e->inf or 0).
__device__ __forceinline__ float ftanh(float x) {
    float e = __expf(2.0f * x);
    return 1.0f - 2.0f * __builtin_amdgcn_rcpf(e + 1.0f);
}

struct Tw16 { vf2 w1, w2, w3, w4, w8, w12; };

// DFT4 (no twiddles): X_m with kernel e^{SGN*2pi i mk/4}
template<int SGN>
__device__ __forceinline__ void dft4(vf2 x0, vf2 x1, vf2 x2, vf2 x3,
                                     vf2& y0, vf2& y1, vf2& y2, vf2& y3) {
    const vf2 nsj = {-(float)SGN, (float)SGN};
    vf2 apc = x0 + x2, amc = x0 - x2;
    vf2 bpd = x1 + x3, bmd = x1 - x3;
    vf2 sj  = nsj * bmd.yx;            // SGN*j*(x1-x3)
    y0 = apc + bpd;
    y1 = amc + sj;
    y2 = apc - bpd;
    y3 = amc - sj;
}

// z[j] = DFT16(x)[j] * w^j; w powers precomputed (fwd values; inv via conj).
template<int SGN>
__device__ __forceinline__ void dft16_tw(const vf2 (&x)[16], const Tw16& tw,
                                         vf2 (&z)[16]) {
    const float S = (float)SGN;
    const vf2 K1 = { 0.9238795325112867f, S * 0.3826834323650898f};
    const vf2 K2 = { 0.7071067811865476f, S * 0.7071067811865476f};
    const vf2 K3 = { 0.3826834323650898f, S * 0.9238795325112867f};
    const vf2 K6 = {-0.7071067811865476f, S * 0.7071067811865476f};
    const vf2 K9 = {-0.9238795325112867f, -S * 0.3826834323650898f};
    const vf2 nsj = {-S, S};
    vf2 u[16];
    {   // layer 1: DFT4 over x[i+4m] -> u[4i+m], internal twiddle K[(i*m)&15]
        vf2 y0, y1, y2, y3;
        dft4<SGN>(x[0], x[4], x[8],  x[12], y0, y1, y2, y3);
        u[0]=y0; u[1]=y1; u[2]=y2; u[3]=y3;
        dft4<SGN>(x[1], x[5], x[9],  x[13], y0, y1, y2, y3);
        u[4]=y0; u[5]=cmul(y1,K1); u[6]=cmul(y2,K2); u[7]=cmul(y3,K3);
        dft4<SGN>(x[2], x[6], x[10], x[14], y0, y1, y2, y3);
        u[8]=y0; u[9]=cmul(y1,K2);
        u[10]= nsj * y2.yx;                           // * e^{SGN*pi i/2}
        u[11]=cmul(y3,K6);
        dft4<SGN>(x[3], x[7], x[11], x[15], y0, y1, y2, y3);
        u[12]=y0; u[13]=cmul(y1,K3); u[14]=cmul(y2,K6); u[15]=cmul(y3,K9);
    }
#pragma unroll
    for (int i = 0; i < 4; ++i) {
        vf2 y0, y1, y2, y3;
        dft4<SGN>(u[i], u[i+4], u[i+8], u[i+12], y0, y1, y2, y3);
        vf2 t1 = cmul_s<SGN>(y1, tw.w4);
        vf2 t2 = cmul_s<SGN>(y2, tw.w8);
        vf2 t3 = cmul_s<SGN>(y3, tw.w12);
        if (i == 0) { z[0] = y0; z[4] = t1; z[8] = t2; z[12] = t3; }
        else {
            vf2 wl = (i == 1) ? tw.w1 : ((i == 2) ? tw.w2 : tw.w3);
            z[i]      = cmul_s<SGN>(y0, wl);
            z[i + 4]  = cmul_s<SGN>(t1, wl);
            z[i + 8]  = cmul_s<SGN>(t2, wl);
            z[i + 12] = cmul_s<SGN>(t3, wl);
        }
    }
}

// IN-PLACE LDS radix-16 Stockham stage (wave-private). lane in [0,64).
template<int SGN, int S>
__device__ __forceinline__ void stage16_ip(vf2* __restrict__ b,
                                           const Tw16& tw, int lane) {
    const int p = lane / S;
    const int q = lane - p * S;
    vf2 x[16];
#pragma unroll
    for (int m = 0; m < 16; ++m) x[m] = b[P(lane + 64 * m)];
    vf2 z[16];
    dft16_tw<SGN>(x, tw, z);
#pragma unroll
    for (int m = 0; m < 16; ++m) b[P(q + 16 * S * p + S * m)] = z[m];
}

// Final radix-4 stage (s=256): twiddle-free, in-place (wave-private).
template<int SGN>
__device__ __forceinline__ void stage4_ip(vf2* __restrict__ buf, int lt) {
#pragma unroll
    for (int r = 0; r < 4; ++r) {
        int i = lt + 64 * r;
        vf2 a = buf[P(i)], b = buf[P(i + 256)], c = buf[P(i + 512)], d = buf[P(i + 768)];
        vf2 y0, y1, y2, y3;
        dft4<SGN>(a, b, c, d, y0, y1, y2, y3);
        buf[P(i)]       = y0;
        buf[P(i + 256)] = y1;
        buf[P(i + 512)] = y2;
        buf[P(i + 768)] = y3;
    }
}

// Forward stage A (s=1): fused global load + Hann window + DFT16 -> LDS.
__device__ __forceinline__ void fwd_stageA(const float* __restrict__ io,
                                           size_t base, int tb,
                                           const vf2* __restrict__ win2,
                                           const Tw16& twA,
                                           vf2* __restrict__ dst, int lt) {
    const vf2 one = {1.f, 1.f};
    vf2 x[16];
#pragma unroll
    for (int m = 0; m < 16; ++m) {
        int n = lt + 64 * m;               // complex slot 0..1023
        int t = tb + 2 * n;
        vf2 v = {0.f, 0.f};
        if (t < TIME_N)
            v = *reinterpret_cast<const vf2*>(io + base + t);
        vf2 wv;
        if (m < 8) wv = win2[n];
        else       wv = one - win2[n - 512];
        x[m] = v * wv;
    }
    vf2 z[16];
    dft16_tw<-1>(x, twA, z);
#pragma unroll
    for (int m = 0; m < 16; ++m) dst[P(16 * lt + m)] = z[m];
}

__global__ __launch_bounds__(512) void stft_chain_kernel(
    const float* __restrict__ transfer,
    const float* __restrict__ gainp,
    float* __restrict__ io)
{
    __shared__ vf2 buf[FCHUNK][BUFSZ];          // 139.3 KB (single, in-place)
    __shared__ vf2 tailbuf[2][512];             // 8 KB raw chunk-crossing tail
    __shared__ vf2 twl[64];                     // 0.5 KB e^{-2pi i j/1024}
    __shared__ vf2 win2[512];                   // 4 KB (win(2m), win(2m+1))

    const int bd  = blockIdx.x;        // 0..255
    const int d   = bd & 63;
    const int tid = threadIdx.x;       // 0..511
    const int lf  = tid >> 6;          // wave id (0..7); owns frames 2lf, 2lf+1
    const int lt  = tid & 63;          // lane within wave
    const float g = gainp[0];
    const size_t base = (size_t)bd * TIME_N;
    const float PI  = 3.14159265358979323846f;
    const float PI2 = 6.2831853071795864769f;
    const float inv = 1.0f / 1024.0f;
    const vf2 cj = {1.f, -1.f};
    const vf2 nm = {-1.f, 1.f};
    const vf2 one = {1.f, 1.f};

    // --- persistent per-thread state: bin pair (tid, 1024-tid) + 512 on t0 ---
    const int kb = (tid == 0) ? 1024 : 1024 - tid;
    const float T0 = transfer[(size_t)d * NBINS + tid];
    const float T1 = transfer[(size_t)d * NBINS + kb];
    const float T5 = (tid == 0) ? transfer[(size_t)d * NBINS + 512] : 0.f;
    vf2 C0 = {0.f, 0.f};
    vf2 C1 = {0.f, 0.f};
    vf2 C5 = {0.f, 0.f};
    float sHt, cHt; __sincosf((PI / HALFN) * (float)tid, &sHt, &cHt);
    const vf2 e2m = {cHt, -sHt};       // e^{-i pi k/1024}
    const vf2 e2p = {cHt,  sHt};       // e^{+i pi m/1024}

    // one-time LDS init
    tailbuf[0][tid] = (vf2){0.f, 0.f};
    tailbuf[1][tid] = (vf2){0.f, 0.f};
    if (tid < 64) {
        float s_, c_; __sincosf(-(PI2 / 1024.0f) * (float)tid, &s_, &c_);
        twl[tid] = (vf2){c_, s_};
    }
    {
        const float cd = __cosf(PI / 1024.0f);
        const float sd = __sinf(PI / 1024.0f);
        float s0, c0; __sincosf((PI / 512.0f) * (float)tid, &s0, &c0);
        float c1 = c0 * cd - s0 * sd;
        win2[tid] = (vf2){0.5f - 0.5f * c0, 0.5f - 0.5f * c1};
    }
    __syncthreads();

    // --- hoisted external twiddle powers (per-lane constants, fwd values) ---
    Tw16 twA, twB;
    {
        vf2 a = twl[lt];                  // stage shape S=1 base
        twA.w1 = a;
        twA.w2 = cmul(a, a);
        twA.w3 = cmul(twA.w2, a);
        twA.w4 = cmul(twA.w2, twA.w2);
        twA.w8 = cmul(twA.w4, twA.w4);
        twA.w12= cmul(twA.w8, twA.w4);
        vf2 b = twl[16 * (lt >> 4)];      // stage shape S=16 base
        twB.w1 = b;
        twB.w2 = cmul(b, b);
        twB.w3 = cmul(twB.w2, b);
        twB.w4 = cmul(twB.w2, twB.w2);
        twB.w8 = cmul(twB.w4, twB.w4);
        twB.w12= cmul(twB.w8, twB.w4);
    }

    for (int ch = 0; ch < NCHUNK; ++ch) {
        const int par = ch & 1;
        const int f0  = 2 * lf;
        const int f1  = 2 * lf + 1;
        const int tb0 = (ch * FCHUNK + f0) * HALFN;
        const int tb1 = tb0 + HALFN;

        // ---- forward FFTs, stage-interleaved across the two owned frames ----
        fwd_stageA(io, base, tb0, win2, twA, &buf[f0][0], lt);
        fwd_stageA(io, base, tb1, win2, twA, &buf[f1][0], lt);
        stage16_ip<-1, 16>(&buf[f0][0], twB, lt);
        stage16_ip<-1, 16>(&buf[f1][0], twB, lt);
        stage4_ip<-1>(&buf[f0][0], lt);
        stage4_ip<-1>(&buf[f1][0], lt);
        __syncthreads();   // #1: all frames' Z ready

        // ---- FUSED rfft-post + scan + irfft-pre, in-place (16 frames) ----
        {
            vf2 Zk = buf[0][P(tid)];
            vf2 Zn = buf[0][P((HALFN - tid) & (HALFN - 1))];
#pragma unroll 2
            for (int f = 0; f < FCHUNK; ++f) {
                vf2 Zk_n, Zn_n;
                if (f < FCHUNK - 1) {
                    Zk_n = buf[f + 1][P(tid)];
                    Zn_n = buf[f + 1][P((HALFN - tid) & (HALFN - 1))];
                }
                vf2 Fe = 0.5f * (Zk + cj * Zn);        // (Zk.x+Zn.x, Zk.y-Zn.y)/2
                vf2 Fo = 0.5f * (cj * Zk.yx + Zn.yx);  // (Zk.y+Zn.y, -(Zk.x-Zn.x))/2
                vf2 U  = cmul(e2m, Fo);
                C0 = (Fe + U + C0) * T0;
                C1 = (cj * (Fe - U) + C1) * T1;
                vf2 Fe2 = 0.5f * (C0 + cj * C1);
                vf2 num = 0.5f * (C0 - cj * C1);
                vf2 Fo2 = cmul(e2p, num);
                buf[f][P(tid)] = Fe2 + nm * Fo2.yx;    // (Fe2.x-Fo2.y, Fe2.y+Fo2.x)
                if (tid != 0) {
                    buf[f][P(HALFN - tid)] = cj * Fe2 + Fo2.yx;
                } else {
                    vf2 Z5 = buf[f][P(512)];
                    C5 = (cj * Z5 + C5) * T5;
                    buf[f][P(512)] = cj * C5;
                }
                Zk = Zk_n; Zn = Zn_n;
            }
        }
        __syncthreads();   // #2: all Z' ready

        // ---- inverse FFTs, stage-interleaved across the two owned frames ----
        stage16_ip<1, 1>(&buf[f0][0], twA, lt);
        stage16_ip<1, 1>(&buf[f1][0], twA, lt);
        stage16_ip<1, 16>(&buf[f0][0], twB, lt);
        stage16_ip<1, 16>(&buf[f1][0], twB, lt);
        stage4_ip<1>(&buf[f0][0], lt);
        stage4_ip<1>(&buf[f1][0], lt);

        // ---- wave 7: stash raw second half of frame 15 for next chunk ----
        if (lf == 7) {
#pragma unroll 2
            for (int j = 0; j < 8; ++j) {
                int m = lt + 64 * j;                   // 0..511
                tailbuf[par][m] = buf[FCHUNK - 1][P(m + 512)];
            }
        }
        __syncthreads();   // #3: inverse results + tail ready

        // ---- phase B: OLA + gain + tanh, both frames ----
        {
#pragma unroll 2
            for (int j = 0; j < 8; ++j) {
                int m = lt + 64 * j;                   // 0..511
                vf2 z0  = buf[f0][P(m)];
                vf2 zp0 = (f0 == 0) ? tailbuf[par ^ 1][m]
                                    : buf[f0 - 1][P(m + 512)];
                vf2 z1  = buf[f1][P(m)];
                vf2 zp1 = buf[f0][P(m + 512)];
                vf2 wf = win2[m];
                vf2 y0v = (z0 * wf + zp0 * (one - wf)) * inv;
                vf2 y1v = (z1 * wf + zp1 * (one - wf)) * inv;
                vf2 o0 = {ftanh(g * y0v.x), ftanh(g * y0v.y)};
                vf2 o1 = {ftanh(g * y1v.x), ftanh(g * y1v.y)};
                *reinterpret_cast<vf2*>(io + base + tb0 + 2 * m) = o0;
                *reinterpret_cast<vf2*>(io + base + tb1 + 2 * m) = o1;
            }
        }
        __syncthreads();   // #4: protect buffers before next chunk's overwrite
    }
}

// ---------------------------------------------------------------------------
extern "C" void kernel_launch(void* const* d_in, const int* in_sizes, int n_in,
                              void* d_out, int out_size, void* d_ws, size_t ws_size,
                              hipStream_t stream) {
    const float* x        = (const float*)d_in[0];   // (4,64,65536)
    const float* transfer = (const float*)d_in[1];   // (64,1025)
    const float* mixer    = (const float*)d_in[2];   // (64,64)
    const float* gain     = (const float*)d_in[3];   // (1,)
    float* out = (float*)d_out;                      // (4,64,65536)

    dim3 g1(TIME_N / 256, 4);
    mix_kernel<<<g1, 256, 0, stream>>>(x, mixer, out);

    stft_chain_kernel<<<256, 512, 0, stream>>>(transfer, gain, out);
}